// Round 1
// baseline (128.773 us; speedup 1.0000x reference)
//
#include <hip/hip_runtime.h>
#include <math.h>

#define HSZ 2048
#define OSZ 1024
#define NGATE 8192  // 4*HSZ

__device__ __forceinline__ float wave_reduce_sum(float v) {
    #pragma unroll
    for (int off = 32; off > 0; off >>= 1)
        v += __shfl_down(v, off, 64);
    return v;
}

struct PreArgs {
    const float* x;      // 1024
    const float* h0; const float* h1; const float* h2; const float* h3; const float* h4;
    const float* Wih1;   // 8192x1024
    const float* W0; const float* W1; const float* W2; const float* W3; const float* W4; // Whh_k 8192x2048
    const float* bi0; const float* bi1; const float* bi2; const float* bi3; const float* bi4;
    const float* bh0; const float* bh1; const float* bh2; const float* bh3; const float* bh4;
    float* pre;          // ws, 5*8192
};

// One wave per (layer k, gate row g). pre[k*8192+g] = Whh_k[g,:]·h_k + bih+bhh (+ Wih1[g,:]·x for k=0)
__global__ __launch_bounds__(256) void k_pre(PreArgs a) {
    const int w    = blockIdx.x * 4 + (threadIdx.x >> 6);  // 0..40959
    const int lane = threadIdx.x & 63;
    const int k = w >> 13;
    const int g = w & (NGATE - 1);

    const float* Whh = (k == 0) ? a.W0 : (k == 1) ? a.W1 : (k == 2) ? a.W2 : (k == 3) ? a.W3 : a.W4;
    const float* hk  = (k == 0) ? a.h0 : (k == 1) ? a.h1 : (k == 2) ? a.h2 : (k == 3) ? a.h3 : a.h4;
    const float* bi  = (k == 0) ? a.bi0 : (k == 1) ? a.bi1 : (k == 2) ? a.bi2 : (k == 3) ? a.bi3 : a.bi4;
    const float* bh  = (k == 0) ? a.bh0 : (k == 1) ? a.bh1 : (k == 2) ? a.bh2 : (k == 3) ? a.bh3 : a.bh4;

    const float4* Wrow = (const float4*)(Whh + (size_t)g * HSZ);
    const float4* hv   = (const float4*)hk;
    float sum = 0.f;
    #pragma unroll
    for (int it = 0; it < 8; ++it) {
        float4 wv = Wrow[it * 64 + lane];
        float4 h4 = hv[it * 64 + lane];
        sum += wv.x * h4.x + wv.y * h4.y + wv.z * h4.z + wv.w * h4.w;
    }
    if (k == 0) {
        const float4* Wr = (const float4*)(a.Wih1 + (size_t)g * OSZ);
        const float4* xv = (const float4*)a.x;
        #pragma unroll
        for (int it = 0; it < 4; ++it) {
            float4 wv = Wr[it * 64 + lane];
            float4 x4 = xv[it * 64 + lane];
            sum += wv.x * x4.x + wv.y * x4.y + wv.z * x4.z + wv.w * x4.w;
        }
    }
    sum = wave_reduce_sum(sum);
    if (lane == 0)
        a.pre[w] = sum + bi[g] + bh[g];
}

// gates[g] += Wih[g,:] · (ya [+ yb]) — one wave per row, 8192 rows
__global__ __launch_bounds__(256) void k_gatex(const float* __restrict__ Wih,
                                               const float* __restrict__ ya,
                                               const float* __restrict__ yb,
                                               float* __restrict__ gates) {
    const int w    = blockIdx.x * 4 + (threadIdx.x >> 6);  // 0..8191
    const int lane = threadIdx.x & 63;
    const float4* Wrow = (const float4*)(Wih + (size_t)w * OSZ);
    const float4* A = (const float4*)ya;
    const float4* B = (const float4*)yb;
    float sum = 0.f;
    #pragma unroll
    for (int it = 0; it < 4; ++it) {
        float4 wv = Wrow[it * 64 + lane];
        float4 av = A[it * 64 + lane];
        if (B) {
            float4 bv = B[it * 64 + lane];
            av.x += bv.x; av.y += bv.y; av.z += bv.z; av.w += bv.w;
        }
        sum += wv.x * av.x + wv.y * av.y + wv.z * av.z + wv.w * av.w;
    }
    sum = wave_reduce_sum(sum);
    if (lane == 0)
        gates[w] += sum;
}

// LSTM cell elementwise: 2048 threads
__global__ __launch_bounds__(256) void k_cell(const float* __restrict__ gates,
                                              const float* __restrict__ c_in,
                                              float* __restrict__ hn,
                                              float* __restrict__ cn) {
    const int j = blockIdx.x * 256 + threadIdx.x;  // grid 8 -> 0..2047
    float gi = gates[j];
    float gf = gates[HSZ + j];
    float gg = gates[2 * HSZ + j];
    float go = gates[3 * HSZ + j];
    float i = 1.f / (1.f + expf(-gi));
    float f = 1.f / (1.f + expf(-gf));
    float g = tanhf(gg);
    float o = 1.f / (1.f + expf(-go));
    float c = c_in[j];
    float cnew = f * c + i * g;
    float hnew = o * tanhf(cnew);
    cn[j] = cnew;
    hn[j] = hnew;
}

// y[j] = Wout[j,:] · h + bout[j] — one wave per row, 1024 rows
__global__ __launch_bounds__(256) void k_head(const float* __restrict__ Wout,
                                              const float* __restrict__ bout,
                                              const float* __restrict__ h,
                                              float* __restrict__ y) {
    const int w    = blockIdx.x * 4 + (threadIdx.x >> 6);  // 0..1023
    const int lane = threadIdx.x & 63;
    const float4* Wrow = (const float4*)(Wout + (size_t)w * HSZ);
    const float4* hv   = (const float4*)h;
    float sum = 0.f;
    #pragma unroll
    for (int it = 0; it < 8; ++it) {
        float4 wv = Wrow[it * 64 + lane];
        float4 h4 = hv[it * 64 + lane];
        sum += wv.x * h4.x + wv.y * h4.y + wv.z * h4.z + wv.w * h4.w;
    }
    sum = wave_reduce_sum(sum);
    if (lane == 0)
        y[w] = sum + bout[w];
}

// softmax over 1024 logits, single block of 1024 threads
__global__ __launch_bounds__(1024) void k_softmax(const float* __restrict__ logits,
                                                  float* __restrict__ out) {
    __shared__ float sm[16];
    __shared__ float ss[16];
    const int t = threadIdx.x;
    const int lane = t & 63;
    const int wid = t >> 6;
    float v = logits[t];
    float m = v;
    #pragma unroll
    for (int off = 32; off > 0; off >>= 1)
        m = fmaxf(m, __shfl_down(m, off, 64));
    if (lane == 0) sm[wid] = m;
    __syncthreads();
    if (t == 0) {
        float mm = sm[0];
        for (int i = 1; i < 16; ++i) mm = fmaxf(mm, sm[i]);
        sm[0] = mm;
    }
    __syncthreads();
    m = sm[0];
    float e = expf(v - m);
    float s = wave_reduce_sum(e);
    if (lane == 0) ss[wid] = s;
    __syncthreads();
    if (t == 0) {
        float tt = 0.f;
        for (int i = 0; i < 16; ++i) tt += ss[i];
        ss[0] = tt;
    }
    __syncthreads();
    out[t] = e / ss[0];
}

extern "C" void kernel_launch(void* const* d_in, const int* in_sizes, int n_in,
                              void* d_out, int out_size, void* d_ws, size_t ws_size,
                              hipStream_t stream) {
    const float* x = (const float*)d_in[0];
    const float* h[5]; const float* c[5];
    for (int k = 0; k < 5; ++k) {
        h[k] = (const float*)d_in[1 + 2 * k];
        c[k] = (const float*)d_in[2 + 2 * k];
    }
    const float* Wih[5]; const float* Whh[5]; const float* bih[5]; const float* bhh[5];
    for (int k = 0; k < 5; ++k) {
        Wih[k] = (const float*)d_in[11 + 4 * k];
        Whh[k] = (const float*)d_in[12 + 4 * k];
        bih[k] = (const float*)d_in[13 + 4 * k];
        bhh[k] = (const float*)d_in[14 + 4 * k];
    }
    const float* Wout = (const float*)d_in[31];
    const float* bout = (const float*)d_in[32];

    float* out = (float*)d_out;              // [0,1024) softmax out
    float* hn[5]; float* cn[5];
    for (int k = 0; k < 5; ++k) {
        hn[k] = out + 1024 + k * 4096;
        cn[k] = hn[k] + 2048;
    }

    float* ws  = (float*)d_ws;
    float* pre = ws;             // 5*8192 floats
    float* y   = ws + 5 * NGATE; // 5*1024 floats

    PreArgs pa;
    pa.x = x;
    pa.h0 = h[0]; pa.h1 = h[1]; pa.h2 = h[2]; pa.h3 = h[3]; pa.h4 = h[4];
    pa.Wih1 = Wih[0];
    pa.W0 = Whh[0]; pa.W1 = Whh[1]; pa.W2 = Whh[2]; pa.W3 = Whh[3]; pa.W4 = Whh[4];
    pa.bi0 = bih[0]; pa.bi1 = bih[1]; pa.bi2 = bih[2]; pa.bi3 = bih[3]; pa.bi4 = bih[4];
    pa.bh0 = bhh[0]; pa.bh1 = bhh[1]; pa.bh2 = bhh[2]; pa.bh3 = bhh[3]; pa.bh4 = bhh[4];
    pa.pre = pre;

    // All recurrent (Whh@h) GEMVs + Wih1@x in parallel: ~352 MB of streaming
    k_pre<<<10240, 256, 0, stream>>>(pa);

    // layer 1
    k_cell<<<8, 256, 0, stream>>>(pre, c[0], hn[0], cn[0]);
    k_head<<<256, 256, 0, stream>>>(Wout, bout, hn[0], y);
    // layer 2 (input y1)
    k_gatex<<<2048, 256, 0, stream>>>(Wih[1], y, nullptr, pre + NGATE);
    k_cell<<<8, 256, 0, stream>>>(pre + NGATE, c[1], hn[1], cn[1]);
    k_head<<<256, 256, 0, stream>>>(Wout, bout, hn[1], y + 1024);
    // layer 3 (input y2+y1)
    k_gatex<<<2048, 256, 0, stream>>>(Wih[2], y + 1024, y, pre + 2 * NGATE);
    k_cell<<<8, 256, 0, stream>>>(pre + 2 * NGATE, c[2], hn[2], cn[2]);
    k_head<<<256, 256, 0, stream>>>(Wout, bout, hn[2], y + 2048);
    // layer 4 (input y3+y2)
    k_gatex<<<2048, 256, 0, stream>>>(Wih[3], y + 2048, y + 1024, pre + 3 * NGATE);
    k_cell<<<8, 256, 0, stream>>>(pre + 3 * NGATE, c[3], hn[3], cn[3]);
    k_head<<<256, 256, 0, stream>>>(Wout, bout, hn[3], y + 3072);
    // layer 5 (input y4+y3)
    k_gatex<<<2048, 256, 0, stream>>>(Wih[4], y + 3072, y + 2048, pre + 4 * NGATE);
    k_cell<<<8, 256, 0, stream>>>(pre + 4 * NGATE, c[4], hn[4], cn[4]);
    k_head<<<256, 256, 0, stream>>>(Wout, bout, hn[4], y + 4096);
    // softmax -> out
    k_softmax<<<1, 1024, 0, stream>>>(y + 4096, out);
}